// Round 1
// baseline (2214.611 us; speedup 1.0000x reference)
//
#include <hip/hip_runtime.h>

#define LL 4096
#define HH 64
#define WWD 64
#define DM 96
#define EE 192
#define NN 16
#define RR 6
#define KBB 8   // N_DIRS * B
#define BB 2

// ---------------- Kernel 1: in_proj GEMM ----------------
// xz[b,l,j] = sum_d x[b,d,l] * W[j,d];  j<192 -> xbuf (B,E,L), j>=192 -> zbuf (B,L,E)
__global__ __launch_bounds__(256) void k_inproj(const float* __restrict__ x,
                                                const float* __restrict__ W,
                                                float* __restrict__ xbuf,
                                                float* __restrict__ zbuf) {
    __shared__ float As[96][64];   // [d][ml]
    __shared__ float Ws[96][64];   // [d][nj]
    int bm = blockIdx.x;           // 0..127 over B*L/64
    int bn = blockIdx.y;           // 0..5 over 384/64
    int l0 = bm * 64;
    int b  = l0 >> 12;
    int lb = l0 & (LL - 1);
    int j0 = bn * 64;
    int t  = threadIdx.x;

    for (int i = t; i < 96 * 64; i += 256) {
        int d = i >> 6, ml = i & 63;
        As[d][ml] = x[((size_t)b * 96 + d) * LL + lb + ml];
    }
    for (int i = t; i < 96 * 64; i += 256) {
        int jn = i / 96, d = i - jn * 96;
        Ws[d][jn] = W[(size_t)(j0 + jn) * 96 + d];
    }
    __syncthreads();

    int tx = t & 15, ty = t >> 4;
    float acc[4][4] = {};
    for (int d = 0; d < 96; d++) {
        float a[4], bbv[4];
        for (int i = 0; i < 4; i++) a[i] = As[d][ty * 4 + i];
        for (int j = 0; j < 4; j++) bbv[j] = Ws[d][tx * 4 + j];
        for (int i = 0; i < 4; i++)
            for (int j = 0; j < 4; j++) acc[i][j] = fmaf(a[i], bbv[j], acc[i][j]);
    }
    for (int i = 0; i < 4; i++) {
        int l = lb + ty * 4 + i;
        for (int j = 0; j < 4; j++) {
            int jj = j0 + tx * 4 + j;
            if (jj < EE)
                xbuf[((size_t)b * EE + jj) * LL + l] = acc[i][j];
            else
                zbuf[((size_t)b * LL + l) * EE + (jj - EE)] = acc[i][j];
        }
    }
}

// ---------------- Kernel 2: depthwise 3x3 conv + bias + SiLU ----------------
__global__ __launch_bounds__(256) void k_conv(const float* __restrict__ xbuf,
                                              const float* __restrict__ cw,
                                              const float* __restrict__ cb,
                                              float* __restrict__ xconv) {
    int i = blockIdx.x * 256 + threadIdx.x;   // over B*E*L
    int pos = i & (LL - 1);
    int be  = i >> 12;
    int e   = be % EE;
    int h = pos >> 6, w = pos & 63;
    const float* src = xbuf + (size_t)be * LL;
    const float* wgt = cw + e * 9;
    float acc = cb[e];
    #pragma unroll
    for (int dh = -1; dh <= 1; dh++) {
        int hh = h + dh;
        if (hh < 0 || hh >= HH) continue;
        #pragma unroll
        for (int dw = -1; dw <= 1; dw++) {
            int w2 = w + dw;
            if (w2 < 0 || w2 >= WWD) continue;
            acc = fmaf(src[hh * WWD + w2], wgt[(dh + 1) * 3 + (dw + 1)], acc);
        }
    }
    xconv[i] = acc / (1.f + __expf(-acc));
}

__device__ __forceinline__ int seq_of_spatial(int k, int idx) {
    // sequence position j for direction k such that u_k[j] = xconv[idx] (involution per k)
    if (k == 0) return idx;
    if (k == 1) return LL - 1 - idx;
    int p = ((idx & 63) << 6) | (idx >> 6);
    if (k == 2) return p;
    return LL - 1 - p;
}

// ---------------- Kernel 3: x_proj + dt_proj + softplus, scatter to sequence order ----------------
__global__ __launch_bounds__(256) void k_proj(const float* __restrict__ xconv,
                                              const float* __restrict__ xpw,
                                              const float* __restrict__ dtw,
                                              const float* __restrict__ dtb,
                                              float* __restrict__ dtbuf,
                                              float* __restrict__ Bbuf,
                                              float* __restrict__ Cbuf) {
    __shared__ float X[EE][65];
    __shared__ float PR[64][40];
    int kb = blockIdx.y;
    int k = kb >> 1, b = kb & 1;
    int t0 = blockIdx.x * 64;  // contiguous spatial tile
    int t = threadIdx.x;

    for (int i = t; i < EE * 64; i += 256) {
        int e = i >> 6, p = i & 63;
        X[e][p] = xconv[((size_t)b * EE + e) * LL + t0 + p];
    }
    __syncthreads();
    {
        int pos = t & 63;
        int obase = t >> 6;
        for (int oo = 0; oo < 40; oo += 4) {
            int out = oo + obase;
            if (out < 38) {
                float s = 0.f;
                const float* wp = xpw + (size_t)k * EE * 38 + out;
                for (int e = 0; e < EE; e++) s = fmaf(X[e][pos], wp[(size_t)e * 38], s);
                PR[pos][out] = s;
            }
        }
    }
    __syncthreads();
    // dt = softplus(dt_low @ dtw^T + bias), layout (kb, j, e)
    for (int i = t; i < 64 * EE; i += 256) {
        int pos = i / EE, e = i - pos * EE;
        float s = dtb[k * EE + e];
        const float* wr = dtw + ((size_t)k * EE + e) * RR;
        #pragma unroll
        for (int r = 0; r < RR; r++) s = fmaf(PR[pos][r], wr[r], s);
        float sp = (s > 20.f) ? s : log1pf(__expf(s));
        int j = seq_of_spatial(k, t0 + pos);
        dtbuf[((size_t)kb * LL + j) * EE + e] = sp;
    }
    // B, C layout (kb, j, n)
    for (int i = t; i < 64 * 32; i += 256) {
        int pos = i >> 5, c = i & 31;
        int j = seq_of_spatial(k, t0 + pos);
        float v = PR[pos][6 + c];
        if (c < 16) Bbuf[((size_t)kb * LL + j) * NN + c] = v;
        else        Cbuf[((size_t)kb * LL + j) * NN + (c - 16)] = v;
    }
}

// ---------------- Kernel 4: selective scan ----------------
// one wave per 4 e-sequences; lane = (e_sub<<4) | n
__global__ __launch_bounds__(64) void k_scan(const float* __restrict__ xconv,
                                             const float* __restrict__ dtbuf,
                                             const float* __restrict__ Bbuf,
                                             const float* __restrict__ Cbuf,
                                             const float* __restrict__ A_log,
                                             const float* __restrict__ Dskip,
                                             float* __restrict__ yo) {
    int blk = blockIdx.x;            // 0..383
    int kb = blk / 48;
    int k = kb >> 1, b = kb & 1;
    int e = (blk % 48) * 4 + (threadIdx.x >> 4);
    int n = threadIdx.x & 15;

    float An = -expf(A_log[e * NN + n]);
    float Dv = Dskip[e];
    const float* ubase  = xconv + ((size_t)b * EE + e) * LL;
    const float* dtbase = dtbuf + (size_t)kb * LL * EE + e;
    const float* Bp     = Bbuf + (size_t)kb * LL * NN + n;
    const float* Cp     = Cbuf + (size_t)kb * LL * NN + n;
    float* yob          = yo + (size_t)b * LL * EE + e;

    float h = 0.f;
    #pragma unroll 2
    for (int l = 0; l < LL; l++) {
        int idx;
        if (k == 0) idx = l;
        else if (k == 1) idx = LL - 1 - l;
        else if (k == 2) idx = ((l & 63) << 6) | (l >> 6);
        else { int j = LL - 1 - l; idx = ((j & 63) << 6) | (j >> 6); }

        float u   = ubase[idx];
        float dtv = dtbase[(size_t)l * EE];
        float Bv  = Bp[(size_t)l * NN];
        float Cv  = Cp[(size_t)l * NN];
        float a = __expf(dtv * An);
        h = fmaf(a, h, dtv * u * Bv);
        float p = h * Cv;
        p += __shfl_xor(p, 1);
        p += __shfl_xor(p, 2);
        p += __shfl_xor(p, 4);
        p += __shfl_xor(p, 8);
        if (n == 0) atomicAdd(&yob[(size_t)idx * EE], p + u * Dv);
    }
}

// ---------------- Kernel 5: LayerNorm + silu(z) gate + out_proj + transpose store ----------------
__global__ __launch_bounds__(256) void k_out(const float* __restrict__ yo,
                                             const float* __restrict__ zb,
                                             const float* __restrict__ gamma,
                                             const float* __restrict__ beta,
                                             const float* __restrict__ W2,
                                             float* __restrict__ out) {
    __shared__ float sbuf[32][193];
    int b  = blockIdx.x >> 7;
    int l0 = (blockIdx.x & 127) * 32;
    int t  = threadIdx.x;
    int wv = t >> 6, lane = t & 63;

    for (int li = 0; li < 32; li += 4) {
        int l = l0 + li + wv;
        const float* yrow = yo + ((size_t)b * LL + l) * EE;
        const float* zrow = zb + ((size_t)b * LL + l) * EE;
        float v[3], zv[3];
        float s = 0.f;
        #pragma unroll
        for (int j = 0; j < 3; j++) {
            v[j] = yrow[lane + 64 * j];
            zv[j] = zrow[lane + 64 * j];
            s += v[j];
        }
        for (int m = 1; m < 64; m <<= 1) s += __shfl_xor(s, m);
        float mu = s * (1.f / EE);
        float q = 0.f;
        #pragma unroll
        for (int j = 0; j < 3; j++) { float d = v[j] - mu; q = fmaf(d, d, q); }
        for (int m = 1; m < 64; m <<= 1) q += __shfl_xor(q, m);
        float rs = rsqrtf(q * (1.f / EE) + 1e-5f);
        #pragma unroll
        for (int j = 0; j < 3; j++) {
            int e = lane + 64 * j;
            float yn = (v[j] - mu) * rs * gamma[e] + beta[e];
            float zz = zv[j];
            float sil = zz / (1.f + __expf(-zz));
            sbuf[li + wv][e] = yn * sil;
        }
    }
    __syncthreads();
    for (int o = t; o < DM * 32; o += 256) {
        int d = o >> 5, c = o & 31;
        const float* wr = W2 + (size_t)d * EE;
        float acc = 0.f;
        for (int e = 0; e < EE; e++) acc = fmaf(sbuf[c][e], wr[e], acc);
        out[((size_t)b * DM + d) * LL + l0 + c] = acc;
    }
}

extern "C" void kernel_launch(void* const* d_in, const int* in_sizes, int n_in,
                              void* d_out, int out_size, void* d_ws, size_t ws_size,
                              hipStream_t stream) {
    const float* x      = (const float*)d_in[0];
    const float* in_w   = (const float*)d_in[1];
    const float* conv_w = (const float*)d_in[2];
    const float* conv_b = (const float*)d_in[3];
    const float* xpw    = (const float*)d_in[4];
    const float* dtw    = (const float*)d_in[5];
    const float* dtbias = (const float*)d_in[6];
    const float* A_log  = (const float*)d_in[7];
    const float* Dsk    = (const float*)d_in[8];
    const float* gamma  = (const float*)d_in[9];
    const float* beta   = (const float*)d_in[10];
    const float* W2     = (const float*)d_in[11];
    float* out = (float*)d_out;

    float* ws    = (float*)d_ws;
    float* xbuf  = ws;                                  // B*E*L
    float* zbuf  = xbuf  + (size_t)BB * EE * LL;        // B*L*E
    float* xconv = zbuf  + (size_t)BB * LL * EE;        // B*E*L
    float* dtbuf = xconv + (size_t)BB * EE * LL;        // KB*L*E
    float* Bbuf  = dtbuf + (size_t)KBB * LL * EE;       // KB*L*N
    float* Cbuf  = Bbuf  + (size_t)KBB * LL * NN;       // KB*L*N
    float* yo    = Cbuf  + (size_t)KBB * LL * NN;       // B*L*E

    hipMemsetAsync(yo, 0, (size_t)BB * LL * EE * sizeof(float), stream);

    k_inproj<<<dim3(128, 6), 256, 0, stream>>>(x, in_w, xbuf, zbuf);
    k_conv<<<(BB * EE * LL) / 256, 256, 0, stream>>>(xbuf, conv_w, conv_b, xconv);
    k_proj<<<dim3(64, 8), 256, 0, stream>>>(xconv, xpw, dtw, dtbias, dtbuf, Bbuf, Cbuf);
    k_scan<<<384, 64, 0, stream>>>(xconv, dtbuf, Bbuf, Cbuf, A_log, Dsk, yo);
    k_out<<<BB * (LL / 32), 256, 0, stream>>>(yo, zbuf, gamma, beta, W2, out);
}

// Round 2
// 419.589 us; speedup vs baseline: 5.2780x; 5.2780x over previous
//
#include <hip/hip_runtime.h>

#define LL 4096
#define HH 64
#define WWD 64
#define DM 96
#define EE 192
#define NN 16
#define RR 6
#define KBB 8   // N_DIRS * B
#define BB 2
#define CH 64   // number of chunks
#define CLEN 64 // chunk length
#define SID (KBB * EE * NN)  // 24576 states

// ---------------- Kernel 1: in_proj GEMM ----------------
__global__ __launch_bounds__(256) void k_inproj(const float* __restrict__ x,
                                                const float* __restrict__ W,
                                                float* __restrict__ xbuf,
                                                float* __restrict__ zbuf) {
    __shared__ float As[96][64];
    __shared__ float Ws[96][64];
    int bm = blockIdx.x;
    int bn = blockIdx.y;
    int l0 = bm * 64;
    int b  = l0 >> 12;
    int lb = l0 & (LL - 1);
    int j0 = bn * 64;
    int t  = threadIdx.x;

    for (int i = t; i < 96 * 64; i += 256) {
        int d = i >> 6, ml = i & 63;
        As[d][ml] = x[((size_t)b * 96 + d) * LL + lb + ml];
    }
    for (int i = t; i < 96 * 64; i += 256) {
        int jn = i / 96, d = i - jn * 96;
        Ws[d][jn] = W[(size_t)(j0 + jn) * 96 + d];
    }
    __syncthreads();

    int tx = t & 15, ty = t >> 4;
    float acc[4][4] = {};
    for (int d = 0; d < 96; d++) {
        float a[4], bbv[4];
        for (int i = 0; i < 4; i++) a[i] = As[d][ty * 4 + i];
        for (int j = 0; j < 4; j++) bbv[j] = Ws[d][tx * 4 + j];
        for (int i = 0; i < 4; i++)
            for (int j = 0; j < 4; j++) acc[i][j] = fmaf(a[i], bbv[j], acc[i][j]);
    }
    for (int i = 0; i < 4; i++) {
        int l = lb + ty * 4 + i;
        for (int j = 0; j < 4; j++) {
            int jj = j0 + tx * 4 + j;
            if (jj < EE)
                xbuf[((size_t)b * EE + jj) * LL + l] = acc[i][j];
            else
                zbuf[((size_t)b * LL + l) * EE + (jj - EE)] = acc[i][j];
        }
    }
}

// ---------------- Kernel 2: depthwise 3x3 conv + bias + SiLU ----------------
__global__ __launch_bounds__(256) void k_conv(const float* __restrict__ xbuf,
                                              const float* __restrict__ cw,
                                              const float* __restrict__ cb,
                                              float* __restrict__ xconv) {
    int i = blockIdx.x * 256 + threadIdx.x;
    int pos = i & (LL - 1);
    int be  = i >> 12;
    int e   = be % EE;
    int h = pos >> 6, w = pos & 63;
    const float* src = xbuf + (size_t)be * LL;
    const float* wgt = cw + e * 9;
    float acc = cb[e];
    #pragma unroll
    for (int dh = -1; dh <= 1; dh++) {
        int hh = h + dh;
        if (hh < 0 || hh >= HH) continue;
        #pragma unroll
        for (int dw = -1; dw <= 1; dw++) {
            int w2 = w + dw;
            if (w2 < 0 || w2 >= WWD) continue;
            acc = fmaf(src[hh * WWD + w2], wgt[(dh + 1) * 3 + (dw + 1)], acc);
        }
    }
    xconv[i] = acc / (1.f + __expf(-acc));
}

__device__ __forceinline__ int seq_of_spatial(int k, int idx) {
    if (k == 0) return idx;
    if (k == 1) return LL - 1 - idx;
    int p = ((idx & 63) << 6) | (idx >> 6);
    if (k == 2) return p;
    return LL - 1 - p;
}

__device__ __forceinline__ int spatial_of_seq(int k, int l) {
    // involution: same formula
    return seq_of_spatial(k, l);
}

// ---------------- Kernel 3: x_proj + dt_proj + softplus ----------------
__global__ __launch_bounds__(256) void k_proj(const float* __restrict__ xconv,
                                              const float* __restrict__ xpw,
                                              const float* __restrict__ dtw,
                                              const float* __restrict__ dtb,
                                              float* __restrict__ dtbuf,
                                              float* __restrict__ Bbuf,
                                              float* __restrict__ Cbuf) {
    __shared__ float X[EE][65];
    __shared__ float PR[64][40];
    int kb = blockIdx.y;
    int k = kb >> 1, b = kb & 1;
    int t0 = blockIdx.x * 64;
    int t = threadIdx.x;

    for (int i = t; i < EE * 64; i += 256) {
        int e = i >> 6, p = i & 63;
        X[e][p] = xconv[((size_t)b * EE + e) * LL + t0 + p];
    }
    __syncthreads();
    {
        int pos = t & 63;
        int obase = t >> 6;
        for (int oo = 0; oo < 40; oo += 4) {
            int out = oo + obase;
            if (out < 38) {
                float s = 0.f;
                const float* wp = xpw + (size_t)k * EE * 38 + out;
                for (int e = 0; e < EE; e++) s = fmaf(X[e][pos], wp[(size_t)e * 38], s);
                PR[pos][out] = s;
            }
        }
    }
    __syncthreads();
    for (int i = t; i < 64 * EE; i += 256) {
        int pos = i / EE, e = i - pos * EE;
        float s = dtb[k * EE + e];
        const float* wr = dtw + ((size_t)k * EE + e) * RR;
        #pragma unroll
        for (int r = 0; r < RR; r++) s = fmaf(PR[pos][r], wr[r], s);
        float sp = (s > 20.f) ? s : log1pf(__expf(s));
        int j = seq_of_spatial(k, t0 + pos);
        dtbuf[((size_t)kb * LL + j) * EE + e] = sp;
    }
    for (int i = t; i < 64 * 32; i += 256) {
        int pos = i >> 5, c = i & 31;
        int j = seq_of_spatial(k, t0 + pos);
        float v = PR[pos][6 + c];
        if (c < 16) Bbuf[((size_t)kb * LL + j) * NN + c] = v;
        else        Cbuf[((size_t)kb * LL + j) * NN + (c - 16)] = v;
    }
}

// ---------------- Kernel 4a: chunk-local scan, emit (prodA, h_end) ----------------
// wave = (kb, chunk c, e-group of 4); lane = (e_sub<<4)|n
__global__ __launch_bounds__(256) void k_scan1(const float* __restrict__ xconv,
                                               const float* __restrict__ dtbuf,
                                               const float* __restrict__ Bbuf,
                                               const float* __restrict__ A_log,
                                               float* __restrict__ Ap,
                                               float* __restrict__ He) {
    int wgid = blockIdx.x * 4 + (threadIdx.x >> 6);
    int lane = threadIdx.x & 63;
    int eg = wgid % 48;
    int c  = (wgid / 48) & 63;
    int kb = wgid / (48 * 64);
    int k = kb >> 1, b = kb & 1;
    int e = eg * 4 + (lane >> 4);
    int n = lane & 15;

    float An = -expf(A_log[e * NN + n]);
    const float* ub  = xconv + ((size_t)b * EE + e) * LL;
    const float* dtp = dtbuf + (size_t)kb * LL * EE + e;
    const float* Bp  = Bbuf + (size_t)kb * LL * NN + n;

    float h = 0.f, pa = 1.f;
    int l0 = c * CLEN;
    #pragma unroll 2
    for (int i = 0; i < CLEN; i++) {
        int l = l0 + i;
        int idx = spatial_of_seq(k, l);
        float u   = ub[idx];
        float dtv = dtp[(size_t)l * EE];
        float Bv  = Bp[(size_t)l * NN];
        float a = __expf(dtv * An);
        h = fmaf(a, h, dtv * u * Bv);
        pa *= a;
    }
    int sid = kb * (EE * NN) + e * NN + n;
    Ap[(size_t)c * SID + sid] = pa;
    He[(size_t)c * SID + sid] = h;
}

// ---------------- Kernel 4b: sequential carry over chunks ----------------
__global__ __launch_bounds__(256) void k_carry(const float* __restrict__ Ap,
                                               const float* __restrict__ He,
                                               float* __restrict__ Hi) {
    int sid = blockIdx.x * 256 + threadIdx.x;   // 0..SID-1
    float h = 0.f;
    #pragma unroll 8
    for (int c = 0; c < CH; c++) {
        Hi[(size_t)c * SID + sid] = h;
        h = fmaf(Ap[(size_t)c * SID + sid], h, He[(size_t)c * SID + sid]);
    }
}

// ---------------- Kernel 4c: chunk-local scan with carry-in, produce y ----------------
__global__ __launch_bounds__(256) void k_scan2(const float* __restrict__ xconv,
                                               const float* __restrict__ dtbuf,
                                               const float* __restrict__ Bbuf,
                                               const float* __restrict__ Cbuf,
                                               const float* __restrict__ A_log,
                                               const float* __restrict__ Dskip,
                                               const float* __restrict__ Hi,
                                               float* __restrict__ yo) {
    int wgid = blockIdx.x * 4 + (threadIdx.x >> 6);
    int lane = threadIdx.x & 63;
    int eg = wgid % 48;
    int c  = (wgid / 48) & 63;
    int kb = wgid / (48 * 64);
    int k = kb >> 1, b = kb & 1;
    int e = eg * 4 + (lane >> 4);
    int n = lane & 15;

    float An = -expf(A_log[e * NN + n]);
    float Dv = Dskip[e];
    const float* ub  = xconv + ((size_t)b * EE + e) * LL;
    const float* dtp = dtbuf + (size_t)kb * LL * EE + e;
    const float* Bp  = Bbuf + (size_t)kb * LL * NN + n;
    const float* Cp  = Cbuf + (size_t)kb * LL * NN + n;
    float* yob       = yo + (size_t)b * LL * EE + e;

    int sid = kb * (EE * NN) + e * NN + n;
    float h = Hi[(size_t)c * SID + sid];
    int l0 = c * CLEN;
    #pragma unroll 2
    for (int i = 0; i < CLEN; i++) {
        int l = l0 + i;
        int idx = spatial_of_seq(k, l);
        float u   = ub[idx];
        float dtv = dtp[(size_t)l * EE];
        float Bv  = Bp[(size_t)l * NN];
        float Cv  = Cp[(size_t)l * NN];
        float a = __expf(dtv * An);
        h = fmaf(a, h, dtv * u * Bv);
        float p = h * Cv;
        p += __shfl_xor(p, 1);
        p += __shfl_xor(p, 2);
        p += __shfl_xor(p, 4);
        p += __shfl_xor(p, 8);
        if (n == 0) atomicAdd(&yob[(size_t)idx * EE], fmaf(u, Dv, p));
    }
}

// ---------------- Kernel 5: LayerNorm + silu(z) gate + out_proj ----------------
__global__ __launch_bounds__(256) void k_out(const float* __restrict__ yo,
                                             const float* __restrict__ zb,
                                             const float* __restrict__ gamma,
                                             const float* __restrict__ beta,
                                             const float* __restrict__ W2,
                                             float* __restrict__ out) {
    __shared__ float sbuf[32][193];
    int b  = blockIdx.x >> 7;
    int l0 = (blockIdx.x & 127) * 32;
    int t  = threadIdx.x;
    int wv = t >> 6, lane = t & 63;

    for (int li = 0; li < 32; li += 4) {
        int l = l0 + li + wv;
        const float* yrow = yo + ((size_t)b * LL + l) * EE;
        const float* zrow = zb + ((size_t)b * LL + l) * EE;
        float v[3], zv[3];
        float s = 0.f;
        #pragma unroll
        for (int j = 0; j < 3; j++) {
            v[j] = yrow[lane + 64 * j];
            zv[j] = zrow[lane + 64 * j];
            s += v[j];
        }
        for (int m = 1; m < 64; m <<= 1) s += __shfl_xor(s, m);
        float mu = s * (1.f / EE);
        float q = 0.f;
        #pragma unroll
        for (int j = 0; j < 3; j++) { float d = v[j] - mu; q = fmaf(d, d, q); }
        for (int m = 1; m < 64; m <<= 1) q += __shfl_xor(q, m);
        float rs = rsqrtf(q * (1.f / EE) + 1e-5f);
        #pragma unroll
        for (int j = 0; j < 3; j++) {
            int e = lane + 64 * j;
            float yn = (v[j] - mu) * rs * gamma[e] + beta[e];
            float zz = zv[j];
            float sil = zz / (1.f + __expf(-zz));
            sbuf[li + wv][e] = yn * sil;
        }
    }
    __syncthreads();
    for (int o = t; o < DM * 32; o += 256) {
        int d = o >> 5, c = o & 31;
        const float* wr = W2 + (size_t)d * EE;
        float acc = 0.f;
        for (int e = 0; e < EE; e++) acc = fmaf(sbuf[c][e], wr[e], acc);
        out[((size_t)b * DM + d) * LL + l0 + c] = acc;
    }
}

extern "C" void kernel_launch(void* const* d_in, const int* in_sizes, int n_in,
                              void* d_out, int out_size, void* d_ws, size_t ws_size,
                              hipStream_t stream) {
    const float* x      = (const float*)d_in[0];
    const float* in_w   = (const float*)d_in[1];
    const float* conv_w = (const float*)d_in[2];
    const float* conv_b = (const float*)d_in[3];
    const float* xpw    = (const float*)d_in[4];
    const float* dtw    = (const float*)d_in[5];
    const float* dtbias = (const float*)d_in[6];
    const float* A_log  = (const float*)d_in[7];
    const float* Dsk    = (const float*)d_in[8];
    const float* gamma  = (const float*)d_in[9];
    const float* beta   = (const float*)d_in[10];
    const float* W2     = (const float*)d_in[11];
    float* out = (float*)d_out;

    float* ws    = (float*)d_ws;
    float* xbuf  = ws;                                  // B*E*L (dead after k_conv -> reused as Ap)
    float* zbuf  = xbuf  + (size_t)BB * EE * LL;        // B*L*E
    float* xconv = zbuf  + (size_t)BB * LL * EE;        // B*E*L
    float* dtbuf = xconv + (size_t)BB * EE * LL;        // KB*L*E
    float* Bbuf  = dtbuf + (size_t)KBB * LL * EE;       // KB*L*N
    float* Cbuf  = Bbuf  + (size_t)KBB * LL * NN;       // KB*L*N
    float* yo    = Cbuf  + (size_t)KBB * LL * NN;       // B*L*E
    float* He    = yo    + (size_t)BB * LL * EE;        // CH*SID
    float* Hi    = He    + (size_t)CH * SID;            // CH*SID
    float* Ap    = xbuf;                                 // reuse (CH*SID == B*E*L)

    hipMemsetAsync(yo, 0, (size_t)BB * LL * EE * sizeof(float), stream);

    k_inproj<<<dim3(128, 6), 256, 0, stream>>>(x, in_w, xbuf, zbuf);
    k_conv<<<(BB * EE * LL) / 256, 256, 0, stream>>>(xbuf, conv_w, conv_b, xconv);
    k_proj<<<dim3(64, 8), 256, 0, stream>>>(xconv, xpw, dtw, dtbias, dtbuf, Bbuf, Cbuf);
    k_scan1<<<(KBB * 48 * CH) / 4, 256, 0, stream>>>(xconv, dtbuf, Bbuf, A_log, Ap, He);
    k_carry<<<SID / 256, 256, 0, stream>>>(Ap, He, Hi);
    k_scan2<<<(KBB * 48 * CH) / 4, 256, 0, stream>>>(xconv, dtbuf, Bbuf, Cbuf, A_log, Dsk, Hi, yo);
    k_out<<<BB * (LL / 32), 256, 0, stream>>>(yo, zbuf, gamma, beta, W2, out);
}

// Round 3
// 289.968 us; speedup vs baseline: 7.6374x; 1.4470x over previous
//
#include <hip/hip_runtime.h>

#define LL 4096
#define HH 64
#define WWD 64
#define DM 96
#define EE 192
#define NN 16
#define RR 6
#define KBB 8   // N_DIRS * B
#define BB 2
#define CH 128  // number of chunks
#define CLEN 32 // chunk length
#define SID (KBB * EE * NN)  // 24576 states

// ---------------- Kernel 1: in_proj GEMM ----------------
__global__ __launch_bounds__(256) void k_inproj(const float* __restrict__ x,
                                                const float* __restrict__ W,
                                                float* __restrict__ xbuf,
                                                float* __restrict__ zbuf) {
    __shared__ float As[96][64];
    __shared__ float Ws[96][64];
    int bm = blockIdx.x;
    int bn = blockIdx.y;
    int l0 = bm * 64;
    int b  = l0 >> 12;
    int lb = l0 & (LL - 1);
    int j0 = bn * 64;
    int t  = threadIdx.x;

    for (int i = t; i < 96 * 64; i += 256) {
        int d = i >> 6, ml = i & 63;
        As[d][ml] = x[((size_t)b * 96 + d) * LL + lb + ml];
    }
    for (int i = t; i < 96 * 64; i += 256) {
        int jn = i / 96, d = i - jn * 96;
        Ws[d][jn] = W[(size_t)(j0 + jn) * 96 + d];
    }
    __syncthreads();

    int tx = t & 15, ty = t >> 4;
    float acc[4][4] = {};
    for (int d = 0; d < 96; d++) {
        float a[4], bbv[4];
        for (int i = 0; i < 4; i++) a[i] = As[d][ty * 4 + i];
        for (int j = 0; j < 4; j++) bbv[j] = Ws[d][tx * 4 + j];
        for (int i = 0; i < 4; i++)
            for (int j = 0; j < 4; j++) acc[i][j] = fmaf(a[i], bbv[j], acc[i][j]);
    }
    for (int i = 0; i < 4; i++) {
        int l = lb + ty * 4 + i;
        for (int j = 0; j < 4; j++) {
            int jj = j0 + tx * 4 + j;
            if (jj < EE)
                xbuf[((size_t)b * EE + jj) * LL + l] = acc[i][j];
            else
                zbuf[((size_t)b * LL + l) * EE + (jj - EE)] = acc[i][j];
        }
    }
}

// ---------------- Kernel 2: depthwise 3x3 conv + bias + SiLU ----------------
__global__ __launch_bounds__(256) void k_conv(const float* __restrict__ xbuf,
                                              const float* __restrict__ cw,
                                              const float* __restrict__ cb,
                                              float* __restrict__ xconv) {
    int i = blockIdx.x * 256 + threadIdx.x;
    int pos = i & (LL - 1);
    int be  = i >> 12;
    int e   = be % EE;
    int h = pos >> 6, w = pos & 63;
    const float* src = xbuf + (size_t)be * LL;
    const float* wgt = cw + e * 9;
    float acc = cb[e];
    #pragma unroll
    for (int dh = -1; dh <= 1; dh++) {
        int hh = h + dh;
        if (hh < 0 || hh >= HH) continue;
        #pragma unroll
        for (int dw = -1; dw <= 1; dw++) {
            int w2 = w + dw;
            if (w2 < 0 || w2 >= WWD) continue;
            acc = fmaf(src[hh * WWD + w2], wgt[(dh + 1) * 3 + (dw + 1)], acc);
        }
    }
    xconv[i] = acc / (1.f + __expf(-acc));
}

__device__ __forceinline__ int seq_of_spatial(int k, int idx) {
    if (k == 0) return idx;
    if (k == 1) return LL - 1 - idx;
    int p = ((idx & 63) << 6) | (idx >> 6);
    if (k == 2) return p;
    return LL - 1 - p;
}

__device__ __forceinline__ int spatial_of_seq(int k, int l) {
    int lp = (k & 1) ? (LL - 1 - l) : l;
    return (k >= 2) ? (((lp & 63) << 6) | (lp >> 6)) : lp;
}

// ---------------- Kernel 3: x_proj + dt_proj + softplus (+ emit xconv_t) ----------------
__global__ __launch_bounds__(256) void k_proj(const float* __restrict__ xconv,
                                              const float* __restrict__ xpw,
                                              const float* __restrict__ dtw,
                                              const float* __restrict__ dtb,
                                              float* __restrict__ dtbuf,
                                              float* __restrict__ Bbuf,
                                              float* __restrict__ Cbuf,
                                              float* __restrict__ xconv_t) {
    __shared__ float X[EE][65];
    __shared__ float PR[64][40];
    int kb = blockIdx.y;
    int k = kb >> 1, b = kb & 1;
    int t0 = blockIdx.x * 64;
    int t = threadIdx.x;

    for (int i = t; i < EE * 64; i += 256) {
        int e = i >> 6, p = i & 63;
        X[e][p] = xconv[((size_t)b * EE + e) * LL + t0 + p];
    }
    __syncthreads();
    // emit transposed copy once per (b, tile): kb==0 -> b=0,k=0; kb==1 -> b=1,k=0
    if (kb < 2) {
        for (int i = t; i < 64 * EE; i += 256) {
            int p = i / EE, e = i - p * EE;
            xconv_t[((size_t)b * LL + t0 + p) * EE + e] = X[e][p];
        }
    }
    {
        int pos = t & 63;
        int obase = t >> 6;
        for (int oo = 0; oo < 40; oo += 4) {
            int out = oo + obase;
            if (out < 38) {
                float s = 0.f;
                const float* wp = xpw + (size_t)k * EE * 38 + out;
                for (int e = 0; e < EE; e++) s = fmaf(X[e][pos], wp[(size_t)e * 38], s);
                PR[pos][out] = s;
            }
        }
    }
    __syncthreads();
    for (int i = t; i < 64 * EE; i += 256) {
        int pos = i / EE, e = i - pos * EE;
        float s = dtb[k * EE + e];
        const float* wr = dtw + ((size_t)k * EE + e) * RR;
        #pragma unroll
        for (int r = 0; r < RR; r++) s = fmaf(PR[pos][r], wr[r], s);
        float sp = (s > 20.f) ? s : log1pf(__expf(s));
        int j = seq_of_spatial(k, t0 + pos);
        dtbuf[((size_t)kb * LL + j) * EE + e] = sp;
    }
    for (int i = t; i < 64 * 32; i += 256) {
        int pos = i >> 5, c = i & 31;
        int j = seq_of_spatial(k, t0 + pos);
        float v = PR[pos][6 + c];
        if (c < 16) Bbuf[((size_t)kb * LL + j) * NN + c] = v;
        else        Cbuf[((size_t)kb * LL + j) * NN + (c - 16)] = v;
    }
}

// ---------------- Kernel 4a: chunk-local scan (16 states/thread), emit (prodA, h_end) ----------------
// block = 192 threads (one e each), one (kb, chunk) per block
__global__ __launch_bounds__(192) void k_scan1(const float* __restrict__ xconv_t,
                                               const float* __restrict__ dtbuf,
                                               const float* __restrict__ Bbuf,
                                               const float* __restrict__ A_log,
                                               float* __restrict__ Ap,
                                               float* __restrict__ He) {
    __shared__ __align__(16) float sB[CLEN][NN];
    int c  = blockIdx.x;
    int kb = blockIdx.y;
    int k = kb >> 1, b = kb & 1;
    int e = threadIdx.x;
    int l0 = c * CLEN;

    for (int i = e; i < CLEN * NN; i += 192)
        ((float*)sB)[i] = Bbuf[((size_t)kb * LL + l0) * NN + i];

    float An[NN], h[NN], pa[NN];
    #pragma unroll
    for (int q = 0; q < 4; q++) {
        float4 al = *(const float4*)&A_log[e * NN + q * 4];
        An[q*4+0] = -__expf(al.x); An[q*4+1] = -__expf(al.y);
        An[q*4+2] = -__expf(al.z); An[q*4+3] = -__expf(al.w);
    }
    #pragma unroll
    for (int n = 0; n < NN; n++) { h[n] = 0.f; pa[n] = 1.f; }
    __syncthreads();

    const float* dtp = dtbuf + ((size_t)kb * LL + l0) * EE + e;
    const float* ub  = xconv_t + (size_t)b * LL * EE + e;

    #pragma unroll 2
    for (int i = 0; i < CLEN; i++) {
        int l = l0 + i;
        int idx = spatial_of_seq(k, l);
        float dtv = dtp[(size_t)i * EE];
        float u   = ub[(size_t)idx * EE];
        float Bv[NN];
        #pragma unroll
        for (int q = 0; q < 4; q++)
            *(float4*)&Bv[q*4] = ((const float4*)&sB[i][0])[q];
        float dtu = dtv * u;
        #pragma unroll
        for (int n = 0; n < NN; n++) {
            float a = __expf(dtv * An[n]);
            h[n] = fmaf(a, h[n], dtu * Bv[n]);
            pa[n] *= a;
        }
    }
    size_t sid = (size_t)c * SID + kb * (EE * NN) + e * NN;
    #pragma unroll
    for (int q = 0; q < 4; q++) {
        *(float4*)&Ap[sid + q*4] = make_float4(pa[q*4], pa[q*4+1], pa[q*4+2], pa[q*4+3]);
        *(float4*)&He[sid + q*4] = make_float4(h[q*4], h[q*4+1], h[q*4+2], h[q*4+3]);
    }
}

// ---------------- Kernel 4b: sequential carry over chunks (Hi written over Ap) ----------------
__global__ __launch_bounds__(256) void k_carry(float* __restrict__ ApHi,
                                               const float* __restrict__ He) {
    int sid = blockIdx.x * 256 + threadIdx.x;
    float h = 0.f;
    #pragma unroll 8
    for (int c = 0; c < CH; c++) {
        size_t ix = (size_t)c * SID + sid;
        float a  = ApHi[ix];
        float he = He[ix];
        ApHi[ix] = h;            // carry-in for chunk c
        h = fmaf(a, h, he);
    }
}

// ---------------- Kernel 4c: chunk-local scan with carry-in, produce y ----------------
__global__ __launch_bounds__(192) void k_scan2(const float* __restrict__ xconv_t,
                                               const float* __restrict__ dtbuf,
                                               const float* __restrict__ Bbuf,
                                               const float* __restrict__ Cbuf,
                                               const float* __restrict__ A_log,
                                               const float* __restrict__ Dskip,
                                               const float* __restrict__ Hi,
                                               float* __restrict__ yo) {
    __shared__ __align__(16) float sB[CLEN][NN];
    __shared__ __align__(16) float sC[CLEN][NN];
    int c  = blockIdx.x;
    int kb = blockIdx.y;
    int k = kb >> 1, b = kb & 1;
    int e = threadIdx.x;
    int l0 = c * CLEN;

    for (int i = e; i < CLEN * NN; i += 192) {
        ((float*)sB)[i] = Bbuf[((size_t)kb * LL + l0) * NN + i];
        ((float*)sC)[i] = Cbuf[((size_t)kb * LL + l0) * NN + i];
    }

    float An[NN], h[NN];
    #pragma unroll
    for (int q = 0; q < 4; q++) {
        float4 al = *(const float4*)&A_log[e * NN + q * 4];
        An[q*4+0] = -__expf(al.x); An[q*4+1] = -__expf(al.y);
        An[q*4+2] = -__expf(al.z); An[q*4+3] = -__expf(al.w);
    }
    size_t sid = (size_t)c * SID + kb * (EE * NN) + e * NN;
    #pragma unroll
    for (int q = 0; q < 4; q++) {
        float4 hv = *(const float4*)&Hi[sid + q*4];
        h[q*4+0] = hv.x; h[q*4+1] = hv.y; h[q*4+2] = hv.z; h[q*4+3] = hv.w;
    }
    float Dv = Dskip[e];
    __syncthreads();

    const float* dtp = dtbuf + ((size_t)kb * LL + l0) * EE + e;
    const float* ub  = xconv_t + (size_t)b * LL * EE + e;
    float* yob       = yo + (size_t)b * LL * EE + e;

    #pragma unroll 2
    for (int i = 0; i < CLEN; i++) {
        int l = l0 + i;
        int idx = spatial_of_seq(k, l);
        float dtv = dtp[(size_t)i * EE];
        float u   = ub[(size_t)idx * EE];
        float Bv[NN], Cv[NN];
        #pragma unroll
        for (int q = 0; q < 4; q++) {
            *(float4*)&Bv[q*4] = ((const float4*)&sB[i][0])[q];
            *(float4*)&Cv[q*4] = ((const float4*)&sC[i][0])[q];
        }
        float dtu = dtv * u;
        float y = u * Dv;
        #pragma unroll
        for (int n = 0; n < NN; n++) {
            float a = __expf(dtv * An[n]);
            h[n] = fmaf(a, h[n], dtu * Bv[n]);
            y = fmaf(h[n], Cv[n], y);
        }
        atomicAdd(&yob[(size_t)idx * EE], y);
    }
}

// ---------------- Kernel 5: LayerNorm + silu(z) gate + out_proj ----------------
__global__ __launch_bounds__(256) void k_out(const float* __restrict__ yo,
                                             const float* __restrict__ zb,
                                             const float* __restrict__ gamma,
                                             const float* __restrict__ beta,
                                             const float* __restrict__ W2,
                                             float* __restrict__ out) {
    __shared__ float sbuf[32][193];
    int b  = blockIdx.x >> 7;
    int l0 = (blockIdx.x & 127) * 32;
    int t  = threadIdx.x;
    int wv = t >> 6, lane = t & 63;

    for (int li = 0; li < 32; li += 4) {
        int l = l0 + li + wv;
        const float* yrow = yo + ((size_t)b * LL + l) * EE;
        const float* zrow = zb + ((size_t)b * LL + l) * EE;
        float v[3], zv[3];
        float s = 0.f;
        #pragma unroll
        for (int j = 0; j < 3; j++) {
            v[j] = yrow[lane + 64 * j];
            zv[j] = zrow[lane + 64 * j];
            s += v[j];
        }
        for (int m = 1; m < 64; m <<= 1) s += __shfl_xor(s, m);
        float mu = s * (1.f / EE);
        float q = 0.f;
        #pragma unroll
        for (int j = 0; j < 3; j++) { float d = v[j] - mu; q = fmaf(d, d, q); }
        for (int m = 1; m < 64; m <<= 1) q += __shfl_xor(q, m);
        float rs = rsqrtf(q * (1.f / EE) + 1e-5f);
        #pragma unroll
        for (int j = 0; j < 3; j++) {
            int e = lane + 64 * j;
            float yn = (v[j] - mu) * rs * gamma[e] + beta[e];
            float zz = zv[j];
            float sil = zz / (1.f + __expf(-zz));
            sbuf[li + wv][e] = yn * sil;
        }
    }
    __syncthreads();
    for (int o = t; o < DM * 32; o += 256) {
        int d = o >> 5, c = o & 31;
        const float* wr = W2 + (size_t)d * EE;
        float acc = 0.f;
        for (int e = 0; e < EE; e++) acc = fmaf(sbuf[c][e], wr[e], acc);
        out[((size_t)b * DM + d) * LL + l0 + c] = acc;
    }
}

extern "C" void kernel_launch(void* const* d_in, const int* in_sizes, int n_in,
                              void* d_out, int out_size, void* d_ws, size_t ws_size,
                              hipStream_t stream) {
    const float* x      = (const float*)d_in[0];
    const float* in_w   = (const float*)d_in[1];
    const float* conv_w = (const float*)d_in[2];
    const float* conv_b = (const float*)d_in[3];
    const float* xpw    = (const float*)d_in[4];
    const float* dtw    = (const float*)d_in[5];
    const float* dtbias = (const float*)d_in[6];
    const float* A_log  = (const float*)d_in[7];
    const float* Dsk    = (const float*)d_in[8];
    const float* gamma  = (const float*)d_in[9];
    const float* beta   = (const float*)d_in[10];
    const float* W2     = (const float*)d_in[11];
    float* out = (float*)d_out;

    float* ws      = (float*)d_ws;
    float* xbuf    = ws;                                   // B*E*L
    float* zbuf    = xbuf    + (size_t)BB * EE * LL;       // B*L*E
    float* xconv   = zbuf    + (size_t)BB * LL * EE;       // B*E*L
    float* xconv_t = xconv   + (size_t)BB * EE * LL;       // B*L*E
    float* dtbuf   = xconv_t + (size_t)BB * LL * EE;       // KB*L*E
    float* Bbuf    = dtbuf   + (size_t)KBB * LL * EE;      // KB*L*N
    float* Cbuf    = Bbuf    + (size_t)KBB * LL * NN;      // KB*L*N
    float* yo      = Cbuf    + (size_t)KBB * LL * NN;      // B*L*E
    float* ApHi    = yo      + (size_t)BB * LL * EE;       // CH*SID (Ap, then Hi in-place)
    float* He      = ApHi    + (size_t)CH * SID;           // CH*SID

    hipMemsetAsync(yo, 0, (size_t)BB * LL * EE * sizeof(float), stream);

    k_inproj<<<dim3(128, 6), 256, 0, stream>>>(x, in_w, xbuf, zbuf);
    k_conv<<<(BB * EE * LL) / 256, 256, 0, stream>>>(xbuf, conv_w, conv_b, xconv);
    k_proj<<<dim3(64, 8), 256, 0, stream>>>(xconv, xpw, dtw, dtbias, dtbuf, Bbuf, Cbuf, xconv_t);
    k_scan1<<<dim3(CH, KBB), 192, 0, stream>>>(xconv_t, dtbuf, Bbuf, A_log, ApHi, He);
    k_carry<<<SID / 256, 256, 0, stream>>>(ApHi, He);
    k_scan2<<<dim3(CH, KBB), 192, 0, stream>>>(xconv_t, dtbuf, Bbuf, Cbuf, A_log, Dsk, ApHi, yo);
    k_out<<<BB * (LL / 32), 256, 0, stream>>>(yo, zbuf, gamma, beta, W2, out);
}